// Round 1
// baseline (391.152 us; speedup 1.0000x reference)
//
#include <hip/hip_runtime.h>
#include <hip/hip_fp16.h>

#define NN 65536
#define KK 2048
#define DD 64

__device__ __forceinline__ unsigned int fkey(float f) {
  unsigned int u = __float_as_uint(f);
  return (u & 0x80000000u) ? ~u : (u | 0x80000000u);
}

// --- K1: normalize codebook -> cbT[64][2048] (transposed), cn2[2048] ---
__global__ void k_norm_cb(const float* __restrict__ cb,
                          float* __restrict__ cbT,
                          float* __restrict__ cn2) {
  int gid = blockIdx.x * blockDim.x + threadIdx.x;
  int row = gid >> 6;   // codebook row, one wave per row
  int lane = gid & 63;  // dim
  float v = cb[row * DD + lane];
  float ss = v * v;
  #pragma unroll
  for (int o = 32; o; o >>= 1) ss += __shfl_xor(ss, o);
  float inv = 1.0f / fmaxf(sqrtf(ss), 1e-12f);
  float cn = v * inv;
  cbT[lane * KK + row] = cn;
  float s2 = cn * cn;
  #pragma unroll
  for (int o = 32; o; o >>= 1) s2 += __shfl_xor(s2, o);
  if (lane == 0) cn2[row] = s2;
}

// --- K2: normalize z rows (transposing gather) -> znT[64][65536] ---
__global__ void k_norm_z(const float* __restrict__ z, float* __restrict__ znT) {
  int wv = threadIdx.x >> 6;
  int w = threadIdx.x & 63;
  int bh = blockIdx.x * 4 + wv;  // (b,h) pair; one wave each
  int b = bh >> 6, h = bh & 63;
  const float* src = z + (size_t)b * 262144 + h * 64 + w;  // z[b][d][h][w]
  float v[64];
  float ss = 0.f;
  #pragma unroll
  for (int d = 0; d < 64; ++d) {
    float x = src[(size_t)d * 4096];
    v[d] = x;
    ss = fmaf(x, x, ss);
  }
  float inv = 1.0f / fmaxf(sqrtf(ss), 1e-12f);
  int n = (bh << 6) | w;  // b*4096 + h*64 + w
  #pragma unroll
  for (int d = 0; d < 64; ++d) znT[(size_t)d * NN + n] = v[d] * inv;
}

// --- K3: fused GEMM + argmin + softmax + prob/q write + loss partial ---
// 16 rows x 2048 codes per block, 256 threads, 8x16 register micro-tile.
__global__ __launch_bounds__(256, 2) void k_main(
    const float* __restrict__ cbT, const float* __restrict__ cn2g,
    const float* __restrict__ znT, float* __restrict__ qout,
    float* __restrict__ prob, float* __restrict__ partials) {
  extern __shared__ char smem[];
  __half* eS = (__half*)smem;                                      // 65536 B  e = exp(2*dot - cn2), fp16
  float* A = (float*)(smem + 65536);                               // 4096 B   A[k][r] = z_norm^T
  unsigned long long* keyS = (unsigned long long*)(smem + 69632);  // 128 B    argmin keys
  float* rowInv = (float*)(smem + 69760);                          // 64 B
  float* wsum = (float*)(smem + 69824);                            // 16 B

  int t = threadIdx.x;
  int n0 = blockIdx.x * 16;

  if (t < 16) keyS[t] = ~0ull;
  {  // stage A[k][r] from znT (coalesced float4)
    int k = t >> 2, qd = (t & 3) << 2;
    float4 v = *(const float4*)(znT + (size_t)k * NN + n0 + qd);
    *(float4*)(A + k * 16 + qd) = v;
  }
  __syncthreads();

  int rb = t >> 7;          // row group (0..1) -> rows rb*8..rb*8+7
  int c0 = (t & 127) << 4;  // 16 codes per thread

  float acc[8][16];
  #pragma unroll
  for (int i = 0; i < 8; ++i)
    #pragma unroll
    for (int j = 0; j < 16; ++j) acc[i][j] = 0.f;

  // P2: K-loop. B from L2-resident cbT, A broadcast from LDS.
  #pragma unroll 2
  for (int k = 0; k < 64; ++k) {
    const float* bp = cbT + k * KK + c0;
    float4 b0 = *(const float4*)(bp);
    float4 b1 = *(const float4*)(bp + 4);
    float4 b2 = *(const float4*)(bp + 8);
    float4 b3 = *(const float4*)(bp + 12);
    const float* ap = A + k * 16 + rb * 8;
    float4 a0 = *(const float4*)(ap);
    float4 a1 = *(const float4*)(ap + 4);
    float a[8] = {a0.x, a0.y, a0.z, a0.w, a1.x, a1.y, a1.z, a1.w};
    float b[16] = {b0.x, b0.y, b0.z, b0.w, b1.x, b1.y, b1.z, b1.w,
                   b2.x, b2.y, b2.z, b2.w, b3.x, b3.y, b3.z, b3.w};
    #pragma unroll
    for (int ri = 0; ri < 8; ++ri)
      #pragma unroll
      for (int ci = 0; ci < 16; ++ci)
        acc[ri][ci] = fmaf(a[ri], b[ci], acc[ri][ci]);
  }

  // P3: exact fp32 argmin (encoded u64, tie -> lowest index) + fp16 exp store
  float cn[16];
  {
    float4 c0v = *(const float4*)(cn2g + c0);
    float4 c1v = *(const float4*)(cn2g + c0 + 4);
    float4 c2v = *(const float4*)(cn2g + c0 + 8);
    float4 c3v = *(const float4*)(cn2g + c0 + 12);
    cn[0] = c0v.x; cn[1] = c0v.y; cn[2] = c0v.z; cn[3] = c0v.w;
    cn[4] = c1v.x; cn[5] = c1v.y; cn[6] = c1v.z; cn[7] = c1v.w;
    cn[8] = c2v.x; cn[9] = c2v.y; cn[10] = c2v.z; cn[11] = c2v.w;
    cn[12] = c3v.x; cn[13] = c3v.y; cn[14] = c3v.z; cn[15] = c3v.w;
  }
  #pragma unroll
  for (int ri = 0; ri < 8; ++ri) {
    int r = rb * 8 + ri;
    unsigned long long bk = ~0ull;
    unsigned int pw[8];
    #pragma unroll
    for (int ci = 0; ci < 16; ci += 2) {
      float d0 = fmaf(-2.f, acc[ri][ci], cn[ci]);       // dist - zn2 (row const dropped)
      float d1 = fmaf(-2.f, acc[ri][ci + 1], cn[ci + 1]);
      unsigned long long k0 = ((unsigned long long)fkey(d0) << 32) | (unsigned)(c0 + ci);
      unsigned long long k1 = ((unsigned long long)fkey(d1) << 32) | (unsigned)(c0 + ci + 1);
      if (k0 < bk) bk = k0;
      if (k1 < bk) bk = k1;
      float e0 = __expf(-d0);  // exp(2*dot - cn2), range [e^-3, e^2]: fp16-safe
      float e1 = __expf(-d1);
      __half2 h2 = __floats2half2_rn(e0, e1);
      pw[ci >> 1] = *reinterpret_cast<unsigned int*>(&h2);
    }
    uint4* dst = (uint4*)(eS + r * KK + c0);
    dst[0] = make_uint4(pw[0], pw[1], pw[2], pw[3]);
    dst[1] = make_uint4(pw[4], pw[5], pw[6], pw[7]);
    atomicMin(&keyS[r], bk);
  }
  __syncthreads();

  // P4: per-row sum of e (deterministic wave reduce)
  {
    int wv = t >> 6, lane = t & 63;
    for (int rr = 0; rr < 4; ++rr) {
      int r = wv * 4 + rr;
      float s = 0.f;
      #pragma unroll
      for (int i = 0; i < 32; ++i) s += __half2float(eS[r * KK + i * 64 + lane]);
      #pragma unroll
      for (int o = 32; o; o >>= 1) s += __shfl_xor(s, o);
      if (lane == 0) rowInv[r] = 1.0f / s;
    }
  }
  __syncthreads();

  // P5: prob = e * (1/S), coalesced fp32 stores (512 MB total)
  {
    float* pr = prob + (size_t)n0 * KK;
    for (int i = 0; i < 128; ++i) {
      int e = i * 256 + t;
      int r = e >> 11;
      pr[e] = __half2float(eS[e]) * rowInv[r];
    }
  }

  // P6: q gather/write + SSD partial (z_norm still live in A)
  {
    int w0 = n0 & 63, hh = (n0 >> 6) & 63, bb = n0 >> 12;
    float ssd = 0.f;
    #pragma unroll
    for (int i = 0; i < 4; ++i) {
      int e = i * 256 + t;
      int d = e >> 4, wi = e & 15;
      int cw = (int)(keyS[wi] & 0xffffffffull);
      float v = cbT[d * KK + cw];
      qout[(size_t)(((bb << 6) | d) * 64 + hh) * 64 + w0 + wi] = v;
      float df = v - A[d * 16 + wi];
      ssd = fmaf(df, df, ssd);
    }
    #pragma unroll
    for (int o = 32; o; o >>= 1) ssd += __shfl_xor(ssd, o);
    int lane = t & 63, wv = t >> 6;
    if (lane == 0) wsum[wv] = ssd;
    __syncthreads();
    if (t == 0) partials[blockIdx.x] = (wsum[0] + wsum[1]) + (wsum[2] + wsum[3]);
  }
}

// --- K4: deterministic loss reduction ---
__global__ void k_final(const float* __restrict__ partials, float* __restrict__ out) {
  __shared__ float wsh[4];
  int t = threadIdx.x;
  float s = 0.f;
  for (int i = 0; i < 16; ++i) s += partials[t * 16 + i];
  #pragma unroll
  for (int o = 32; o; o >>= 1) s += __shfl_xor(s, o);
  if ((t & 63) == 0) wsh[t >> 6] = s;
  __syncthreads();
  if (t == 0) {
    float tot = (wsh[0] + wsh[1]) + (wsh[2] + wsh[3]);
    float cbl = tot * (1.0f / 4194304.0f);  // mean over n*d
    out[4194304] = 1.25f * cbl;  // loss = cb + 0.25*commit, commit == cb
    out[4194305] = cbl;
    out[4194306] = cbl;
  }
}

extern "C" void kernel_launch(void* const* d_in, const int* in_sizes, int n_in,
                              void* d_out, int out_size, void* d_ws, size_t ws_size,
                              hipStream_t stream) {
  const float* z = (const float*)d_in[0];
  const float* cb = (const float*)d_in[1];
  float* out = (float*)d_out;
  char* ws = (char*)d_ws;

  float* cbT = (float*)(ws);                 // 524288 B
  float* cn2 = (float*)(ws + 524288);        // 8192 B
  float* partials = (float*)(ws + 532480);   // 16384 B
  float* znT = (float*)(ws + 548864);        // 16 MB

  const int SMEM = 69840;
  hipFuncSetAttribute((const void*)k_main, hipFuncAttributeMaxDynamicSharedMemorySize, SMEM);

  k_norm_cb<<<512, 256, 0, stream>>>(cb, cbT, cn2);
  k_norm_z<<<256, 256, 0, stream>>>(z, znT);
  k_main<<<4096, 256, SMEM, stream>>>(cbT, cn2, znT, out, out + 4194307, partials);
  k_final<<<1, 256, 0, stream>>>(partials, out);
}

// Round 2
// 363.299 us; speedup vs baseline: 1.0767x; 1.0767x over previous
//
#include <hip/hip_runtime.h>

#define NN 65536
#define KK 2048
#define DD 64

__device__ __forceinline__ unsigned int fkey(float f) {
  unsigned int u = __float_as_uint(f);
  return (u & 0x80000000u) ? ~u : (u | 0x80000000u);
}

// --- K1: normalize codebook -> cbT[64][2048] (transposed), cn2[2048] ---
__global__ void k_norm_cb(const float* __restrict__ cb,
                          float* __restrict__ cbT,
                          float* __restrict__ cn2) {
  int gid = blockIdx.x * blockDim.x + threadIdx.x;
  int row = gid >> 6;   // codebook row, one wave per row
  int lane = gid & 63;  // dim
  float v = cb[row * DD + lane];
  float ss = v * v;
  #pragma unroll
  for (int o = 32; o; o >>= 1) ss += __shfl_xor(ss, o);
  float inv = 1.0f / fmaxf(sqrtf(ss), 1e-12f);
  float cn = v * inv;
  cbT[lane * KK + row] = cn;
  float s2 = cn * cn;
  #pragma unroll
  for (int o = 32; o; o >>= 1) s2 += __shfl_xor(s2, o);
  if (lane == 0) cn2[row] = s2;
}

// --- K2: fused normalize-z + GEMM + argmin + softmax + prob/q + loss ---
// 16 z-rows x 2048 codes per block, 512 threads.
// Each thread: all 16 rows x 4 unique cols (cols t*4..t*4+3). acc[16][4].
__global__ __launch_bounds__(512, 4) void k_main(
    const float* __restrict__ z, const float* __restrict__ cbT,
    const float* __restrict__ cn2g, float* __restrict__ qout,
    float* __restrict__ prob, float* __restrict__ partials) {
  __shared__ float A[64 * 16];          // A[k*16+r] = z_norm^T tile
  __shared__ float normpart[16 * 16];
  __shared__ float rowpart[16 * 8];
  __shared__ unsigned long long keyS[16];
  __shared__ float normInv[16];
  __shared__ float rowInvS[16];
  __shared__ float wsum[8];

  int t = threadIdx.x;
  int lane = t & 63, wv = t >> 6;
  int n0 = blockIdx.x * 16;
  int w0 = n0 & 63, hh = (n0 >> 6) & 63, bb = n0 >> 12;

  if (t < 16) keyS[t] = ~0ull;

  // Phase A: stage raw z tile (16 consecutive w, fixed b,h), normalize in LDS
  if (t < 256) {
    int k = t >> 2, qd = (t & 3) << 2;
    const float* src = z + (size_t)bb * 262144 + (size_t)k * 4096 + hh * 64 + w0 + qd;
    float4 v = *(const float4*)src;
    *(float4*)(A + k * 16 + qd) = v;
  }
  __syncthreads();
  if (t < 256) {
    int r = t >> 4, c = t & 15;
    float s = 0.f;
    #pragma unroll
    for (int i = 0; i < 4; ++i) {
      float x = A[(c * 4 + i) * 16 + r];
      s = fmaf(x, x, s);
    }
    normpart[r * 16 + c] = s;
  }
  __syncthreads();
  if (t < 16) {
    float s = 0.f;
    #pragma unroll
    for (int c = 0; c < 16; ++c) s += normpart[t * 16 + c];
    normInv[t] = 1.0f / fmaxf(sqrtf(s), 1e-12f);
  }
  __syncthreads();
  if (t < 256) {
    int k = t >> 2, qd = (t & 3) << 2;
    #pragma unroll
    for (int i = 0; i < 4; ++i) A[k * 16 + qd + i] *= normInv[qd + i];
  }
  __syncthreads();

  // Phase B: K-loop. B float4 per thread (unique cols), A broadcast from LDS.
  float acc[16][4];
  #pragma unroll
  for (int r = 0; r < 16; ++r)
    #pragma unroll
    for (int j = 0; j < 4; ++j) acc[r][j] = 0.f;

  const float* bptr = cbT + (t << 2);
  #pragma unroll 2
  for (int k = 0; k < 64; ++k) {
    float4 bv = *(const float4*)(bptr);
    bptr += KK;
    const float* ap = A + (k << 4);
    float4 a0 = *(const float4*)(ap);
    float4 a1 = *(const float4*)(ap + 4);
    float4 a2 = *(const float4*)(ap + 8);
    float4 a3 = *(const float4*)(ap + 12);
    float ar[16] = {a0.x, a0.y, a0.z, a0.w, a1.x, a1.y, a1.z, a1.w,
                    a2.x, a2.y, a2.z, a2.w, a3.x, a3.y, a3.z, a3.w};
    #pragma unroll
    for (int r = 0; r < 16; ++r) {
      acc[r][0] = fmaf(ar[r], bv.x, acc[r][0]);
      acc[r][1] = fmaf(ar[r], bv.y, acc[r][1]);
      acc[r][2] = fmaf(ar[r], bv.z, acc[r][2]);
      acc[r][3] = fmaf(ar[r], bv.w, acc[r][3]);
    }
  }

  // Phase C: per-row d -> exact argmin key + e=exp(-d) (overwrite acc) + row sums
  float4 cnv = *(const float4*)(cn2g + (t << 2));
  float cn[4] = {cnv.x, cnv.y, cnv.z, cnv.w};
  unsigned int c0 = t << 2;

  #pragma unroll
  for (int r = 0; r < 16; ++r) {
    float d0 = fmaf(-2.f, acc[r][0], cn[0]);  // dist - zn2 (row const dropped)
    float d1 = fmaf(-2.f, acc[r][1], cn[1]);
    float d2 = fmaf(-2.f, acc[r][2], cn[2]);
    float d3 = fmaf(-2.f, acc[r][3], cn[3]);
    unsigned long long k0 = ((unsigned long long)fkey(d0) << 32) | (c0 + 0);
    unsigned long long k1 = ((unsigned long long)fkey(d1) << 32) | (c0 + 1);
    unsigned long long k2 = ((unsigned long long)fkey(d2) << 32) | (c0 + 2);
    unsigned long long k3 = ((unsigned long long)fkey(d3) << 32) | (c0 + 3);
    if (k1 < k0) k0 = k1;
    if (k3 < k2) k2 = k3;
    if (k2 < k0) k0 = k2;
    acc[r][0] = __expf(-d0);
    acc[r][1] = __expf(-d1);
    acc[r][2] = __expf(-d2);
    acc[r][3] = __expf(-d3);
    float s = (acc[r][0] + acc[r][1]) + (acc[r][2] + acc[r][3]);
    #pragma unroll
    for (int o = 32; o; o >>= 1) s += __shfl_xor(s, o);
    if (lane == 0) rowpart[r * 8 + wv] = s;
    #pragma unroll
    for (int o = 1; o <= 4; o <<= 1) {
      unsigned long long ok = __shfl_xor(k0, o);
      if (ok < k0) k0 = ok;
    }
    if ((lane & 7) == 0) atomicMin(&keyS[r], k0);
  }
  __syncthreads();
  if (t < 16) {
    float s = 0.f;
    #pragma unroll
    for (int w = 0; w < 8; ++w) s += rowpart[t * 8 + w];
    rowInvS[t] = 1.0f / s;
  }
  __syncthreads();

  // Phase D: prob = e * (1/S), contiguous float4 stores per wave
  {
    float* pr = prob + (size_t)n0 * KK + (t << 2);
    #pragma unroll
    for (int r = 0; r < 16; ++r) {
      float inv = rowInvS[r];
      float4 o = make_float4(acc[r][0] * inv, acc[r][1] * inv,
                             acc[r][2] * inv, acc[r][3] * inv);
      *(float4*)pr = o;
      pr += KK;
    }
  }

  // Phase E: q gather/write + SSD partial (z_norm live in A)
  {
    float ssd = 0.f;
    #pragma unroll
    for (int i = 0; i < 2; ++i) {
      int e = t + i * 512;  // 0..1023 over (d, wi)
      int d = e >> 4, wi = e & 15;
      int cw = (int)(keyS[wi] & 0xffffffffull);
      float v = cbT[d * KK + cw];
      qout[((size_t)((bb << 6) | d) * 64 + hh) * 64 + w0 + wi] = v;
      float df = v - A[d * 16 + wi];
      ssd = fmaf(df, df, ssd);
    }
    #pragma unroll
    for (int o = 32; o; o >>= 1) ssd += __shfl_xor(ssd, o);
    if (lane == 0) wsum[wv] = ssd;
    __syncthreads();
    if (t == 0) {
      float s = ((wsum[0] + wsum[1]) + (wsum[2] + wsum[3])) +
                ((wsum[4] + wsum[5]) + (wsum[6] + wsum[7]));
      partials[blockIdx.x] = s;
    }
  }
}

// --- K3: deterministic loss reduction ---
__global__ void k_final(const float* __restrict__ partials, float* __restrict__ out) {
  __shared__ float wsh[4];
  int t = threadIdx.x;
  float s = 0.f;
  for (int i = 0; i < 16; ++i) s += partials[t * 16 + i];
  #pragma unroll
  for (int o = 32; o; o >>= 1) s += __shfl_xor(s, o);
  if ((t & 63) == 0) wsh[t >> 6] = s;
  __syncthreads();
  if (t == 0) {
    float tot = (wsh[0] + wsh[1]) + (wsh[2] + wsh[3]);
    float cbl = tot * (1.0f / 4194304.0f);  // mean over n*d
    out[4194304] = 1.25f * cbl;  // loss = cb + 0.25*commit (commit == cb numerically)
    out[4194305] = cbl;
    out[4194306] = cbl;
  }
}

extern "C" void kernel_launch(void* const* d_in, const int* in_sizes, int n_in,
                              void* d_out, int out_size, void* d_ws, size_t ws_size,
                              hipStream_t stream) {
  const float* z = (const float*)d_in[0];
  const float* cb = (const float*)d_in[1];
  float* out = (float*)d_out;
  char* ws = (char*)d_ws;

  float* cbT = (float*)(ws);                // 524288 B
  float* cn2 = (float*)(ws + 524288);       // 8192 B
  float* partials = (float*)(ws + 532480);  // 16384 B

  k_norm_cb<<<512, 256, 0, stream>>>(cb, cbT, cn2);
  k_main<<<4096, 512, 0, stream>>>(z, cbT, cn2, out, out + 4194307, partials);
  k_final<<<1, 256, 0, stream>>>(partials, out);
}